// Round 8
// baseline (15.199 us; speedup 1.0000x reference)
//
#include <hip/hip_runtime.h>

#define SIZE 512
#define NTRI 512

#pragma clang fp contract(off)

__device__ __forceinline__ float lin_at(int i) {
    // Replicates jnp.linspace(-1, 1, 512): for i < 511,
    // s = i/511 (f32 correctly-rounded div), out = (-1)*(1-s) + 1*s = s - (1-s).
    // Endpoint i == 511 is exactly 1.0.
    if (i == SIZE - 1) return 1.0f;
    float s = __fdiv_rn((float)i, 511.0f);
    float u = 1.0f - s;
    return s - u;
}

// Bit-exact reference epilogue for the winning triangle (true division, exact op order).
__device__ __forceinline__ float4 shade(const float* __restrict__ tris, int bi,
                                        float px, float py) {
#pragma clang fp contract(off)
    if (bi < 0) return make_float4(0.0f, 0.0f, 0.0f, 0.0f);
    const float* p = tris + bi * 9;
    float a0 = p[0], a1 = p[1], a2 = p[2];
    float b0 = p[3], b1 = p[4], b2 = p[5];
    float c0 = p[6], c1 = p[7], c2 = p[8];
    float w = (b0 - a0) * (c1 - a1) - (b1 - a1) * (c0 - a0);
    float sw = (fabsf(w) > 1e-8f) ? w : 1.0f;
    float dax = a0 - px, day = a1 - py;
    float dbx = b0 - px, dby = b1 - py;
    float dcx = c0 - px, dcy = c1 - py;
    float pAB = dax * dby - day * dbx;
    float pBC = dbx * dcy - dby * dcx;
    float w1 = __fdiv_rn(pAB, sw);
    float w2 = __fdiv_rn(pBC, sw);
    float w3 = 1.0f - w1 - w2;
    float x = (w1 * a0 + w2 * b0) + w3 * c0;
    float y = (w1 * a1 + w2 * b1) + w3 * c1;
    float z = (w1 * a2 + w2 * b2) + w3 * c2;
    return make_float4(x, y, z, 1.0f);
}

__global__ __launch_bounds__(512, 8) void render_kernel(const float* __restrict__ tris,
                                                        float* __restrict__ out) {
#pragma clang fp contract(off)
    __shared__ float4 szp[NTRI];   // zc, zx, zy, bitcast(t)   (all classes, compacted)
    __shared__ int4   sbb[NTRI];   // int bbox                 (classes IP, EX)
    __shared__ float4 sv0[NTRI];   // a0, a1, b0, b1           (class EX)
    __shared__ float2 sv1[NTRI];   // c0, c1                   (class EX)
    __shared__ unsigned long long smA[8], smB[8], smC[8];
    __shared__ float sredz[8], sredm[8];
    __shared__ float2 smrg[256];   // (best, bitcast t) from the h==1 half

    const int tid = threadIdx.x;         // 0..511
    const int lane = tid & 63, wv = tid >> 6;
    const unsigned long long lt = (1ull << lane) - 1ull;

    const int i0 = blockIdx.y * 16;
    const int j0 = blockIdx.x * 16;

    const float pxlo = lin_at(i0), pxhi = lin_at(i0 + 15);
    const float pylo = lin_at(j0), pyhi = lin_at(j0 + 15);

    // ---- phase 1: ONE tri per thread: preprocess, cull, classify, z-bounds ----
    const int t = tid;
    const float* p = tris + t * 9;
    float a0 = p[0], a1 = p[1], a2 = p[2];
    float b0 = p[3], b1 = p[4], b2 = p[5];
    float c0 = p[6], c1 = p[7], c2 = p[8];

    float zm = fminf(a2, fminf(b2, c2));   // global z-min contribution

    float w = (b0 - a0) * (c1 - a1) - (b1 - a1) * (c0 - a0);
    bool vw = fabsf(w) > 1e-8f;
    float sw = vw ? w : 1.0f;

    float lox = fminf(fminf(a0, b0), c0);
    float loy = fminf(fminf(a1, b1), c1);
    float hix = fmaxf(fmaxf(a0, b0), c0);
    float hiy = fmaxf(fmaxf(a1, b1), c1);
    int bb0 = (int)((fminf(fmaxf(lox, -1.0f), 1.0f) + 1.0f) * 0.5f * 512.0f);
    int bb1 = (int)((fminf(fmaxf(loy, -1.0f), 1.0f) + 1.0f) * 0.5f * 512.0f);
    int bb2 = (int)((fminf(fmaxf(hix, -1.0f), 1.0f) + 1.0f) * 0.5f * 512.0f);
    int bb3 = (int)((fminf(fmaxf(hiy, -1.0f), 1.0f) + 1.0f) * 0.5f * 512.0f);

    // Winding cull (pAB+pBC+pCA == w algebraically) + bbox-vs-tile cull.
    bool cand = vw && (w > -1e-4f) &&
                (bb0 < i0 + 16) && (bb2 > i0) &&
                (bb1 < j0 + 16) && (bb3 > j0);

    // Edge consts (rect tests AND z-plane).
    float cAB = a0 * b1 - a1 * b0, gxAB = a1 - b1, gyAB = b0 - a0;
    float cBC = b0 * c1 - b1 * c0, gxBC = b1 - c1, gyBC = c0 - b0;
    float cCA = c0 * a1 - c1 * a0, gxCA = c1 - a1, gyCA = a0 - c0;

    // Edge-vs-tile rect: max over rect < -1e-3 -> cull; min > +1e-3 ->
    // edge certainly positive at every tile pixel (guard >> 1.5e-5 fp bound).
    bool allIn = false;
    if (cand) {
        float x0, x1, y0, y1, mx, mn;
        x0 = gxAB * pxlo; x1 = gxAB * pxhi; y0 = gyAB * pylo; y1 = gyAB * pyhi;
        mx = cAB + fmaxf(x0, x1) + fmaxf(y0, y1);
        mn = cAB + fminf(x0, x1) + fminf(y0, y1);
        cand = mx >= -1e-3f;
        allIn = mn > 1e-3f;
        x0 = gxBC * pxlo; x1 = gxBC * pxhi; y0 = gyBC * pylo; y1 = gyBC * pyhi;
        mx = cBC + fmaxf(x0, x1) + fmaxf(y0, y1);
        mn = cBC + fminf(x0, x1) + fminf(y0, y1);
        cand = cand && (mx >= -1e-3f);
        allIn = allIn && (mn > 1e-3f);
        x0 = gxCA * pxlo; x1 = gxCA * pxhi; y0 = gyCA * pylo; y1 = gyCA * pyhi;
        mx = cCA + fmaxf(x0, x1) + fmaxf(y0, y1);
        mn = cCA + fminf(x0, x1) + fminf(y0, y1);
        cand = cand && (mx >= -1e-3f);
        allIn = allIn && (mn > 1e-3f);
    }

    // z-plane (selection-only precision: fast rcp; shade recomputes exactly).
    float rsw = __builtin_amdgcn_rcpf(sw);
    float k1 = (a2 - c2) * rsw;
    float k2 = (b2 - c2) * rsw;
    float zc = c2 + k1 * cAB + k2 * cBC;
    float zx = k1 * gxAB + k2 * gxBC;
    float zy = k1 * gyAB + k2 * gyBC;

    // Certified z-bounds of the plane over the tile rect.
    float zxl = zx * pxlo, zxh = zx * pxhi;
    float zyl = zy * pylo, zyh = zy * pyhi;
    float tzmin = zc + fminf(zxl, zxh) + fminf(zyl, zyh);
    float tzmax = zc + fmaxf(zxl, zxh) + fmaxf(zyl, zyh);

    bool full = (bb0 <= i0) && (bb2 >= i0 + 16) &&
                (bb1 <= j0) && (bb3 >= j0 + 16);
    bool vIF = cand && allIn && full;      // covers every tile pixel
    bool vIP = cand && allIn && !full;
    bool vEX = cand && !allIn;

    // Hierarchical-Z basis: only full-coverage candidates dominate everywhere.
    float mloc = vIF ? tzmin : -1e30f;

    // Joint block reductions: zmin (min) and M (max of IF tile-zmins). Exact ops.
    for (int off = 32; off; off >>= 1) {
        zm = fminf(zm, __shfl_xor(zm, off));
        mloc = fmaxf(mloc, __shfl_xor(mloc, off));
    }
    if (lane == 0) { sredz[wv] = zm; sredm[wv] = mloc; }
    __syncthreads();
    float zmin = sredz[0], M = sredm[0];
#pragma unroll
    for (int g = 1; g < 8; ++g) { zmin = fminf(zmin, sredz[g]); M = fmaxf(M, sredm[g]); }
    // Any candidate with tzmax < max(M, zmin) - 1e-4 can never win a pixel
    // (dominating IF plane >= M - 2e-6 everywhere; guard >> fp discrepancy).
    const float cullb = fmaxf(M, zmin) - 1e-4f;

    // ---- hier-Z cull, ballots ----
    {
        bool keep = tzmax >= cullb;
        vIF &= keep; vIP &= keep; vEX &= keep;
        unsigned long long mA = __ballot(vIF);
        unsigned long long mB = __ballot(vIP);
        unsigned long long mC = __ballot(vEX);
        if (lane == 0) { smA[wv] = mA; smB[wv] = mB; smC[wv] = mC; }
    }
    __syncthreads();

    // ---- phase 2: ordered scatter into 3 compacted segments ----
    int bA[8], bB[8], bC[8], c = 0;
#pragma unroll
    for (int g = 0; g < 8; ++g) { bA[g] = c; c += __popcll(smA[g]); }
    const int cntA = c;
#pragma unroll
    for (int g = 0; g < 8; ++g) { bB[g] = c; c += __popcll(smB[g]); }
    const int cntB = c;
#pragma unroll
    for (int g = 0; g < 8; ++g) { bC[g] = c; c += __popcll(smC[g]); }
    const int cntC = c;

    if (vIF || vIP || vEX) {
        int pos;
        if (vIF)      pos = bA[wv] + __popcll(smA[wv] & lt);
        else if (vIP) pos = bB[wv] + __popcll(smB[wv] & lt);
        else          pos = bC[wv] + __popcll(smC[wv] & lt);

        szp[pos] = make_float4(zc, zx, zy, __int_as_float(t));
        if (!vIF) sbb[pos] = make_int4(bb0, bb1, bb2, bb3);
        if (vEX) {
            sv0[pos] = make_float4(a0, a1, b0, b1);
            sv1[pos] = make_float2(c0, c1);
        }
    }
    __syncthreads();

    // ---- phase 3: 2 threads per pixel; each walks half of every segment ----
    const int pix = tid & 255;
    const int h   = tid >> 8;            // 0 or 1: stride-2 offset
    const int tx  = pix & 15;
    const int tyq = pix >> 4;
    const int j = j0 + tx;
    const int i = i0 + tyq;
    const float px = lin_at(i);
    const float py = lin_at(j);

    float best = zmin;
    int   bt = -1;

    // S1: interior + full bbox: z-plane only. (ascending t within half: >= == larger-t wins)
#pragma unroll 4
    for (int k = h; k < cntA; k += 2) {
        float4 zp = szp[k];
        float z = fmaf(zp.y, px, fmaf(zp.z, py, zp.x));
        if (z >= best) { best = z; bt = __float_as_int(zp.w); }
    }
    // S2: interior + partial bbox.
#pragma unroll 4
    for (int k = cntA + h; k < cntB; k += 2) {
        float4 zp = szp[k];
        int4 bb = sbb[k];
        float z = fmaf(zp.y, px, fmaf(zp.z, py, zp.x));
        bool in = (i >= bb.x) & (i < bb.z) & (j >= bb.y) & (j < bb.w);
        if (in & (z >= best)) { best = z; bt = __float_as_int(zp.w); }
    }
    // S3: exact edge evaluation (reference op order) + bbox.
#pragma unroll 2
    for (int k = cntB + h; k < cntC; k += 2) {
        float4 zp = szp[k];
        float4 f0 = sv0[k];
        float2 f1 = sv1[k];
        int4 bb = sbb[k];
        float dax = f0.x - px, day = f0.y - py;
        float dbx = f0.z - px, dby = f0.w - py;
        float dcx = f1.x - px, dcy = f1.y - py;
        float pAB = dax * dby - day * dbx;
        float pBC = dbx * dcy - dby * dcx;
        float pCA = dcx * day - dcy * dax;
        bool cov = (pAB > 0.0f) & (pBC > 0.0f) & (pCA > 0.0f) &
                   (i >= bb.x) & (i < bb.z) & (j >= bb.y) & (j < bb.w);
        float z = fmaf(zp.y, px, fmaf(zp.z, py, zp.x));
        if (cov & (z >= best)) { best = z; bt = __float_as_int(zp.w); }
    }

    // ---- merge halves (lexicographic (z, t): reference's larger-t-wins ties) ----
    if (h == 1) smrg[pix] = make_float2(best, __int_as_float(bt));
    __syncthreads();
    if (h == 0) {
        float2 o = smrg[pix];
        float zB = o.x;
        int tB = __float_as_int(o.y);
        if ((zB > best) | ((zB == best) & (tB > bt))) { best = zB; bt = tB; }
        // ---- epilogue: bit-exact shade of winner ----
        ((float4*)out)[i * SIZE + j] = shade(tris, bt, px, py);
    }
}

extern "C" void kernel_launch(void* const* d_in, const int* in_sizes, int n_in,
                              void* d_out, int out_size, void* d_ws, size_t ws_size,
                              hipStream_t stream) {
    const float* tris = (const float*)d_in[0];
    float* out = (float*)d_out;
    dim3 grid(SIZE / 16, SIZE / 16, 1);
    dim3 block(512, 1, 1);
    render_kernel<<<grid, block, 0, stream>>>(tris, out);
}

// Round 9
// 12.847 us; speedup vs baseline: 1.1830x; 1.1830x over previous
//
#include <hip/hip_runtime.h>

#define SIZE 512
#define NTRI 512

#pragma clang fp contract(off)

__device__ __forceinline__ float lin_at(int i) {
    // Replicates jnp.linspace(-1, 1, 512): for i < 511,
    // s = i/511 (f32 correctly-rounded div), out = (-1)*(1-s) + 1*s = s - (1-s).
    // Endpoint i == 511 is exactly 1.0.
    if (i == SIZE - 1) return 1.0f;
    float s = __fdiv_rn((float)i, 511.0f);
    float u = 1.0f - s;
    return s - u;
}

// Bit-exact reference epilogue (true division, exact op order), reading the
// verbatim LDS copy of tris.
__device__ __forceinline__ float4 shade_lds(const float* __restrict__ st, int bi,
                                            float px, float py) {
#pragma clang fp contract(off)
    if (bi < 0) return make_float4(0.0f, 0.0f, 0.0f, 0.0f);
    const float* p = st + bi * 9;
    float a0 = p[0], a1 = p[1], a2 = p[2];
    float b0 = p[3], b1 = p[4], b2 = p[5];
    float c0 = p[6], c1 = p[7], c2 = p[8];
    float w = (b0 - a0) * (c1 - a1) - (b1 - a1) * (c0 - a0);
    float sw = (fabsf(w) > 1e-8f) ? w : 1.0f;
    float dax = a0 - px, day = a1 - py;
    float dbx = b0 - px, dby = b1 - py;
    float dcx = c0 - px, dcy = c1 - py;
    float pAB = dax * dby - day * dbx;
    float pBC = dbx * dcy - dby * dcx;
    float w1 = __fdiv_rn(pAB, sw);
    float w2 = __fdiv_rn(pBC, sw);
    float w3 = 1.0f - w1 - w2;
    float x = (w1 * a0 + w2 * b0) + w3 * c0;
    float y = (w1 * a1 + w2 * b1) + w3 * c1;
    float z = (w1 * a2 + w2 * b2) + w3 * c2;
    return make_float4(x, y, z, 1.0f);
}

__global__ __launch_bounds__(256) void render_kernel(const float* __restrict__ tris,
                                                     float* __restrict__ out) {
#pragma clang fp contract(off)
    __shared__ float  stris[NTRI * 9];  // verbatim tri data (coalesced staged)
    __shared__ float4 szp[NTRI];        // zc, zx, zy, bitcast(t) (compacted)
    __shared__ int4   sbb[NTRI];        // int bbox (classes IP, EX)
    __shared__ unsigned long long smA[8], smB[8], smC[8];
    __shared__ float sredz[4], sredm[4];

    const int tx = threadIdx.x;          // 0..15 -> j offset
    const int ty = threadIdx.y;          // 0..15 -> i offset
    const int tid = ty * 16 + tx;        // 0..255
    const int lane = tid & 63, wv = tid >> 6;
    const unsigned long long lt = (1ull << lane) - 1ull;

    const int i0 = blockIdx.y * 16;
    const int j0 = blockIdx.x * 16;

    const float pxlo = lin_at(i0), pxhi = lin_at(i0 + 15);
    const float pylo = lin_at(j0), pyhi = lin_at(j0 + 15);

    // ---- phase 0: coalesced stage of all tris into LDS (1152 float4) ----
    {
        const float4* g4 = (const float4*)tris;
        float4* s4 = (float4*)stris;
        for (int k = tid; k < NTRI * 9 / 4; k += 256) s4[k] = g4[k];
    }
    __syncthreads();

    // ---- phase 1: 2 tris/thread from LDS: preprocess, cull, classify ----
    float vzc[2], vzx[2], vzy[2], vtzx[2];
    int   vx0[2], vy0[2], vx1[2], vy1[2];
    bool  vIF[2], vIP[2], vEX[2];

    float zm = 1e30f;       // global z-min (background init)
    float mloc = -1e30f;    // max over full-coverage candidates of tile-zmin
#pragma unroll
    for (int r = 0; r < 2; ++r) {
        const int t = tid + r * 256;
        const float* p = &stris[t * 9];
        float a0 = p[0], a1 = p[1], a2 = p[2];
        float b0 = p[3], b1 = p[4], b2 = p[5];
        float c0 = p[6], c1 = p[7], c2 = p[8];

        zm = fminf(zm, fminf(a2, fminf(b2, c2)));

        float w = (b0 - a0) * (c1 - a1) - (b1 - a1) * (c0 - a0);
        bool vw = fabsf(w) > 1e-8f;
        float sw = vw ? w : 1.0f;

        float lox = fminf(fminf(a0, b0), c0);
        float loy = fminf(fminf(a1, b1), c1);
        float hix = fmaxf(fmaxf(a0, b0), c0);
        float hiy = fmaxf(fmaxf(a1, b1), c1);
        int bb0 = (int)((fminf(fmaxf(lox, -1.0f), 1.0f) + 1.0f) * 0.5f * 512.0f);
        int bb1 = (int)((fminf(fmaxf(loy, -1.0f), 1.0f) + 1.0f) * 0.5f * 512.0f);
        int bb2 = (int)((fminf(fmaxf(hix, -1.0f), 1.0f) + 1.0f) * 0.5f * 512.0f);
        int bb3 = (int)((fminf(fmaxf(hiy, -1.0f), 1.0f) + 1.0f) * 0.5f * 512.0f);
        vx0[r] = bb0; vy0[r] = bb1; vx1[r] = bb2; vy1[r] = bb3;

        // Winding cull (pAB+pBC+pCA == w algebraically) + bbox-vs-tile cull.
        bool cand = vw && (w > -1e-4f) &&
                    (bb0 < i0 + 16) && (bb2 > i0) &&
                    (bb1 < j0 + 16) && (bb3 > j0);

        // Edge consts (rect tests AND z-plane).
        float cAB = a0 * b1 - a1 * b0, gxAB = a1 - b1, gyAB = b0 - a0;
        float cBC = b0 * c1 - b1 * c0, gxBC = b1 - c1, gyBC = c0 - b0;
        float cCA = c0 * a1 - c1 * a0, gxCA = c1 - a1, gyCA = a0 - c0;

        // Edge-vs-tile rect: max over rect < -1e-3 -> cull; min > +1e-3 ->
        // edge certainly positive at every tile pixel (guard >> 1.5e-5 fp bound).
        bool allIn = false;
        if (cand) {
            float x0, x1, y0, y1, mx, mn;
            x0 = gxAB * pxlo; x1 = gxAB * pxhi; y0 = gyAB * pylo; y1 = gyAB * pyhi;
            mx = cAB + fmaxf(x0, x1) + fmaxf(y0, y1);
            mn = cAB + fminf(x0, x1) + fminf(y0, y1);
            cand = mx >= -1e-3f;
            allIn = mn > 1e-3f;
            x0 = gxBC * pxlo; x1 = gxBC * pxhi; y0 = gyBC * pylo; y1 = gyBC * pyhi;
            mx = cBC + fmaxf(x0, x1) + fmaxf(y0, y1);
            mn = cBC + fminf(x0, x1) + fminf(y0, y1);
            cand = cand && (mx >= -1e-3f);
            allIn = allIn && (mn > 1e-3f);
            x0 = gxCA * pxlo; x1 = gxCA * pxhi; y0 = gyCA * pylo; y1 = gyCA * pyhi;
            mx = cCA + fmaxf(x0, x1) + fmaxf(y0, y1);
            mn = cCA + fminf(x0, x1) + fminf(y0, y1);
            cand = cand && (mx >= -1e-3f);
            allIn = allIn && (mn > 1e-3f);
        }

        // z-plane (selection-only precision: fast rcp; shade recomputes exactly).
        float rsw = __builtin_amdgcn_rcpf(sw);
        float k1 = (a2 - c2) * rsw;
        float k2 = (b2 - c2) * rsw;
        float zc = c2 + k1 * cAB + k2 * cBC;
        float zx = k1 * gxAB + k2 * gxBC;
        float zy = k1 * gyAB + k2 * gyBC;
        vzc[r] = zc; vzx[r] = zx; vzy[r] = zy;

        // Certified z-bounds of the plane over the tile rect.
        float zxl = zx * pxlo, zxh = zx * pxhi;
        float zyl = zy * pylo, zyh = zy * pyhi;
        float tzmin = zc + fminf(zxl, zxh) + fminf(zyl, zyh);
        float tzmax = zc + fmaxf(zxl, zxh) + fmaxf(zyl, zyh);
        vtzx[r] = tzmax;

        bool full = (bb0 <= i0) && (bb2 >= i0 + 16) &&
                    (bb1 <= j0) && (bb3 >= j0 + 16);
        vIF[r] = cand && allIn && full;     // covers every tile pixel
        vIP[r] = cand && allIn && !full;
        vEX[r] = cand && !allIn;

        // Hierarchical-Z basis: only full-coverage candidates dominate everywhere.
        if (vIF[r]) mloc = fmaxf(mloc, tzmin);
    }

    // Joint block reductions: zmin (min) and M (max of IF tile-zmins). Exact ops.
    for (int off = 32; off; off >>= 1) {
        zm = fminf(zm, __shfl_xor(zm, off));
        mloc = fmaxf(mloc, __shfl_xor(mloc, off));
    }
    if (lane == 0) { sredz[wv] = zm; sredm[wv] = mloc; }
    __syncthreads();
    const float zmin = fminf(fminf(sredz[0], sredz[1]), fminf(sredz[2], sredz[3]));
    const float M = fmaxf(fmaxf(sredm[0], sredm[1]), fmaxf(sredm[2], sredm[3]));
    // Any candidate with tzmax < max(M, zmin) - 1e-4 can never win a pixel
    // (dominating IF plane >= M - 2e-6 everywhere; guard >> fp discrepancy).
    const float cullb = fmaxf(M, zmin) - 1e-4f;

    // ---- apply hier-Z cull, then ballots ----
#pragma unroll
    for (int r = 0; r < 2; ++r) {
        bool keep = vtzx[r] >= cullb;
        vIF[r] &= keep; vIP[r] &= keep; vEX[r] &= keep;
        unsigned long long mA = __ballot(vIF[r]);
        unsigned long long mB = __ballot(vIP[r]);
        unsigned long long mC = __ballot(vEX[r]);
        if (lane == 0) { smA[r * 4 + wv] = mA; smB[r * 4 + wv] = mB; smC[r * 4 + wv] = mC; }
    }
    __syncthreads();

    // ---- phase 2: ordered scatter into 3 compacted segments ----
    int bA[8], bB[8], bC[8], c = 0;
#pragma unroll
    for (int g = 0; g < 8; ++g) { bA[g] = c; c += __popcll(smA[g]); }
    const int cntA = c;
#pragma unroll
    for (int g = 0; g < 8; ++g) { bB[g] = c; c += __popcll(smB[g]); }
    const int cntB = c;
#pragma unroll
    for (int g = 0; g < 8; ++g) { bC[g] = c; c += __popcll(smC[g]); }
    const int cntC = c;

#pragma unroll
    for (int r = 0; r < 2; ++r) {
        if (vIF[r] || vIP[r] || vEX[r]) {
            const int g = r * 4 + wv;
            const int t = tid + r * 256;
            int pos;
            if (vIF[r])      pos = bA[g] + __popcll(smA[g] & lt);
            else if (vIP[r]) pos = bB[g] + __popcll(smB[g] & lt);
            else             pos = bC[g] + __popcll(smC[g] & lt);

            szp[pos] = make_float4(vzc[r], vzx[r], vzy[r], __int_as_float(t));
            if (!vIF[r]) sbb[pos] = make_int4(vx0[r], vy0[r], vx1[r], vy1[r]);
        }
    }
    __syncthreads();

    // ---- phase 3: per-pixel loop, 1 pixel/thread, 3 segments ----
    const int j = j0 + tx;
    const int i = i0 + ty;
    const float px = lin_at(i);
    const float py = lin_at(j);

    float best = zmin;
    int   bt = -1;

    // S1: interior + full bbox: z-plane only.
#pragma unroll 4
    for (int k = 0; k < cntA; ++k) {
        float4 zp = szp[k];
        float z = fmaf(zp.y, px, fmaf(zp.z, py, zp.x));
        if (z >= best) { best = z; bt = __float_as_int(zp.w); }
    }
    // S2: interior + partial bbox.
#pragma unroll 4
    for (int k = cntA; k < cntB; ++k) {
        float4 zp = szp[k];
        int4 bb = sbb[k];
        float z = fmaf(zp.y, px, fmaf(zp.z, py, zp.x));
        bool in = (i >= bb.x) & (i < bb.z) & (j >= bb.y) & (j < bb.w);
        if (in & (z >= best)) { best = z; bt = __float_as_int(zp.w); }
    }
    // S3: exact edge evaluation (reference op order) + bbox; vertex data read
    // from the LDS tri copy at wave-uniform index (broadcast, conflict-free).
#pragma unroll 2
    for (int k = cntB; k < cntC; ++k) {
        float4 zp = szp[k];
        int4 bb = sbb[k];
        const int tt = __float_as_int(zp.w);
        const float* q = &stris[tt * 9];
        float a0 = q[0], a1 = q[1];
        float b0 = q[3], b1 = q[4];
        float c0 = q[6], c1 = q[7];
        float dax = a0 - px, day = a1 - py;
        float dbx = b0 - px, dby = b1 - py;
        float dcx = c0 - px, dcy = c1 - py;
        float pAB = dax * dby - day * dbx;
        float pBC = dbx * dcy - dby * dcx;
        float pCA = dcx * day - dcy * dax;
        bool cov = (pAB > 0.0f) & (pBC > 0.0f) & (pCA > 0.0f) &
                   (i >= bb.x) & (i < bb.z) & (j >= bb.y) & (j < bb.w);
        float z = fmaf(zp.y, px, fmaf(zp.z, py, zp.x));
        if (cov & (z >= best)) { best = z; bt = __float_as_int(zp.w); }
    }

    // ---- epilogue: bit-exact shade of winner (from LDS copy) ----
    ((float4*)out)[i * SIZE + j] = shade_lds(stris, bt, px, py);
}

extern "C" void kernel_launch(void* const* d_in, const int* in_sizes, int n_in,
                              void* d_out, int out_size, void* d_ws, size_t ws_size,
                              hipStream_t stream) {
    const float* tris = (const float*)d_in[0];
    float* out = (float*)d_out;
    dim3 grid(SIZE / 16, SIZE / 16, 1);
    dim3 block(16, 16, 1);
    render_kernel<<<grid, block, 0, stream>>>(tris, out);
}

// Round 10
// 12.485 us; speedup vs baseline: 1.2174x; 1.0290x over previous
//
#include <hip/hip_runtime.h>

#define SIZE 512
#define NTRI 512

#pragma clang fp contract(off)

__device__ __forceinline__ float lin_at(int i) {
    // Replicates jnp.linspace(-1, 1, 512): for i < 511,
    // s = i/511 (f32 correctly-rounded div), out = (-1)*(1-s) + 1*s = s - (1-s).
    // Endpoint i == 511 is exactly 1.0.
    if (i == SIZE - 1) return 1.0f;
    float s = __fdiv_rn((float)i, 511.0f);
    float u = 1.0f - s;
    return s - u;
}

// Bit-exact reference epilogue (true division, exact op order), reading the
// verbatim LDS copy of tris.
__device__ __forceinline__ float4 shade_lds(const float* __restrict__ st, int bi,
                                            float px, float py) {
#pragma clang fp contract(off)
    if (bi < 0) return make_float4(0.0f, 0.0f, 0.0f, 0.0f);
    const float* p = st + bi * 9;
    float a0 = p[0], a1 = p[1], a2 = p[2];
    float b0 = p[3], b1 = p[4], b2 = p[5];
    float c0 = p[6], c1 = p[7], c2 = p[8];
    float w = (b0 - a0) * (c1 - a1) - (b1 - a1) * (c0 - a0);
    float sw = (fabsf(w) > 1e-8f) ? w : 1.0f;
    float dax = a0 - px, day = a1 - py;
    float dbx = b0 - px, dby = b1 - py;
    float dcx = c0 - px, dcy = c1 - py;
    float pAB = dax * dby - day * dbx;
    float pBC = dbx * dcy - dby * dcx;
    float w1 = __fdiv_rn(pAB, sw);
    float w2 = __fdiv_rn(pBC, sw);
    float w3 = 1.0f - w1 - w2;
    float x = (w1 * a0 + w2 * b0) + w3 * c0;
    float y = (w1 * a1 + w2 * b1) + w3 * c1;
    float z = (w1 * a2 + w2 * b2) + w3 * c2;
    return make_float4(x, y, z, 1.0f);
}

__global__ __launch_bounds__(512) void render_kernel(const float* __restrict__ tris,
                                                     float* __restrict__ out) {
#pragma clang fp contract(off)
    __shared__ float  stris[NTRI * 9];  // verbatim tri data (coalesced staged)
    __shared__ float4 szp[NTRI];        // zc, zx, zy, bitcast(t) (compacted)
    __shared__ int4   sbb[NTRI];        // int bbox (classes IP, EX)
    __shared__ unsigned long long smA[8], smB[8], smC[8];
    __shared__ float sredz[8], sredm[8];

    const int tid = threadIdx.x;         // 0..511
    const int lane = tid & 63, wv = tid >> 6;
    const unsigned long long lt = (1ull << lane) - 1ull;

    const int i0 = blockIdx.y * 32;
    const int j0 = blockIdx.x * 32;

    const float pxlo = lin_at(i0), pxhi = lin_at(i0 + 31);
    const float pylo = lin_at(j0), pyhi = lin_at(j0 + 31);

    // ---- phase 0: coalesced stage of all tris into LDS (1152 float4) ----
    {
        const float4* g4 = (const float4*)tris;
        float4* s4 = (float4*)stris;
        for (int k = tid; k < NTRI * 9 / 4; k += 512) s4[k] = g4[k];
    }
    __syncthreads();

    // ---- phase 1: ONE tri per thread from LDS: preprocess, cull, classify ----
    const int t = tid;
    const float* p = &stris[t * 9];
    float a0 = p[0], a1 = p[1], a2 = p[2];
    float b0 = p[3], b1 = p[4], b2 = p[5];
    float c0 = p[6], c1 = p[7], c2 = p[8];

    float zm = fminf(a2, fminf(b2, c2));   // global z-min contribution

    float w = (b0 - a0) * (c1 - a1) - (b1 - a1) * (c0 - a0);
    bool vw = fabsf(w) > 1e-8f;
    float sw = vw ? w : 1.0f;

    float lox = fminf(fminf(a0, b0), c0);
    float loy = fminf(fminf(a1, b1), c1);
    float hix = fmaxf(fmaxf(a0, b0), c0);
    float hiy = fmaxf(fmaxf(a1, b1), c1);
    int bb0 = (int)((fminf(fmaxf(lox, -1.0f), 1.0f) + 1.0f) * 0.5f * 512.0f);
    int bb1 = (int)((fminf(fmaxf(loy, -1.0f), 1.0f) + 1.0f) * 0.5f * 512.0f);
    int bb2 = (int)((fminf(fmaxf(hix, -1.0f), 1.0f) + 1.0f) * 0.5f * 512.0f);
    int bb3 = (int)((fminf(fmaxf(hiy, -1.0f), 1.0f) + 1.0f) * 0.5f * 512.0f);

    // Winding cull (pAB+pBC+pCA == w algebraically) + bbox-vs-tile cull.
    bool cand = vw && (w > -1e-4f) &&
                (bb0 < i0 + 32) && (bb2 > i0) &&
                (bb1 < j0 + 32) && (bb3 > j0);

    // Edge consts (rect tests AND z-plane).
    float cAB = a0 * b1 - a1 * b0, gxAB = a1 - b1, gyAB = b0 - a0;
    float cBC = b0 * c1 - b1 * c0, gxBC = b1 - c1, gyBC = c0 - b0;
    float cCA = c0 * a1 - c1 * a0, gxCA = c1 - a1, gyCA = a0 - c0;

    // Edge-vs-tile rect: max over rect < -1e-3 -> cull; min > +1e-3 ->
    // edge certainly positive at every tile pixel (guard >> 1.5e-5 fp bound).
    bool allIn = false;
    if (cand) {
        float x0, x1, y0, y1, mx, mn;
        x0 = gxAB * pxlo; x1 = gxAB * pxhi; y0 = gyAB * pylo; y1 = gyAB * pyhi;
        mx = cAB + fmaxf(x0, x1) + fmaxf(y0, y1);
        mn = cAB + fminf(x0, x1) + fminf(y0, y1);
        cand = mx >= -1e-3f;
        allIn = mn > 1e-3f;
        x0 = gxBC * pxlo; x1 = gxBC * pxhi; y0 = gyBC * pylo; y1 = gyBC * pyhi;
        mx = cBC + fmaxf(x0, x1) + fmaxf(y0, y1);
        mn = cBC + fminf(x0, x1) + fminf(y0, y1);
        cand = cand && (mx >= -1e-3f);
        allIn = allIn && (mn > 1e-3f);
        x0 = gxCA * pxlo; x1 = gxCA * pxhi; y0 = gyCA * pylo; y1 = gyCA * pyhi;
        mx = cCA + fmaxf(x0, x1) + fmaxf(y0, y1);
        mn = cCA + fminf(x0, x1) + fminf(y0, y1);
        cand = cand && (mx >= -1e-3f);
        allIn = allIn && (mn > 1e-3f);
    }

    // z-plane (selection-only precision: fast rcp; shade recomputes exactly).
    float rsw = __builtin_amdgcn_rcpf(sw);
    float k1 = (a2 - c2) * rsw;
    float k2 = (b2 - c2) * rsw;
    float zc = c2 + k1 * cAB + k2 * cBC;
    float zx = k1 * gxAB + k2 * gxBC;
    float zy = k1 * gyAB + k2 * gyBC;

    // Certified z-bounds of the plane over the tile rect.
    float zxl = zx * pxlo, zxh = zx * pxhi;
    float zyl = zy * pylo, zyh = zy * pyhi;
    float tzmin = zc + fminf(zxl, zxh) + fminf(zyl, zyh);
    float tzmax = zc + fmaxf(zxl, zxh) + fmaxf(zyl, zyh);

    bool full = (bb0 <= i0) && (bb2 >= i0 + 32) &&
                (bb1 <= j0) && (bb3 >= j0 + 32);
    bool vIF = cand && allIn && full;      // covers every tile pixel
    bool vIP = cand && allIn && !full;
    bool vEX = cand && !allIn;

    // Hierarchical-Z basis: only full-coverage candidates dominate everywhere.
    float mloc = vIF ? tzmin : -1e30f;

    // Joint block reductions: zmin (min) and M (max of IF tile-zmins). Exact ops.
    for (int off = 32; off; off >>= 1) {
        zm = fminf(zm, __shfl_xor(zm, off));
        mloc = fmaxf(mloc, __shfl_xor(mloc, off));
    }
    if (lane == 0) { sredz[wv] = zm; sredm[wv] = mloc; }
    __syncthreads();
    float zmin = sredz[0], M = sredm[0];
#pragma unroll
    for (int g = 1; g < 8; ++g) { zmin = fminf(zmin, sredz[g]); M = fmaxf(M, sredm[g]); }
    // Any candidate with tzmax < max(M, zmin) - 1e-4 can never win a pixel
    // (dominating IF plane >= M - 2e-6 everywhere; guard >> fp discrepancy).
    const float cullb = fmaxf(M, zmin) - 1e-4f;

    // ---- hier-Z cull, ballots ----
    {
        bool keep = tzmax >= cullb;
        vIF &= keep; vIP &= keep; vEX &= keep;
        unsigned long long mA = __ballot(vIF);
        unsigned long long mB = __ballot(vIP);
        unsigned long long mC = __ballot(vEX);
        if (lane == 0) { smA[wv] = mA; smB[wv] = mB; smC[wv] = mC; }
    }
    __syncthreads();

    // ---- phase 2: ordered scatter into 3 compacted segments ----
    int bA[8], bB[8], bC[8], c = 0;
#pragma unroll
    for (int g = 0; g < 8; ++g) { bA[g] = c; c += __popcll(smA[g]); }
    const int cntA = c;
#pragma unroll
    for (int g = 0; g < 8; ++g) { bB[g] = c; c += __popcll(smB[g]); }
    const int cntB = c;
#pragma unroll
    for (int g = 0; g < 8; ++g) { bC[g] = c; c += __popcll(smC[g]); }
    const int cntC = c;

    if (vIF || vIP || vEX) {
        int pos;
        if (vIF)      pos = bA[wv] + __popcll(smA[wv] & lt);
        else if (vIP) pos = bB[wv] + __popcll(smB[wv] & lt);
        else          pos = bC[wv] + __popcll(smC[wv] & lt);

        szp[pos] = make_float4(zc, zx, zy, __int_as_float(t));
        if (!vIF) sbb[pos] = make_int4(bb0, bb1, bb2, bb3);
    }
    __syncthreads();

    // ---- phase 3: 2 pixels/thread (rows i and i+16), 3 segments ----
    const int tx  = tid & 31;            // j offset 0..31
    const int tyq = tid >> 5;            // i offset 0..15
    const int j  = j0 + tx;
    const int iA = i0 + tyq;
    const int iB = iA + 16;
    const float pxA = lin_at(iA);
    const float pxB = lin_at(iB);
    const float py  = lin_at(j);

    float bestA = zmin, bestB = zmin;
    int   btA = -1,     btB = -1;

    // S1: interior + full bbox: z-plane only.
#pragma unroll 4
    for (int k = 0; k < cntA; ++k) {
        float4 zp = szp[k];
        float base = fmaf(zp.z, py, zp.x);
        float zA = fmaf(zp.y, pxA, base);
        float zB = fmaf(zp.y, pxB, base);
        if (zA >= bestA) { bestA = zA; btA = __float_as_int(zp.w); }
        if (zB >= bestB) { bestB = zB; btB = __float_as_int(zp.w); }
    }
    // S2: interior + partial bbox.
#pragma unroll 4
    for (int k = cntA; k < cntB; ++k) {
        float4 zp = szp[k];
        int4 bb = sbb[k];
        float base = fmaf(zp.z, py, zp.x);
        float zA = fmaf(zp.y, pxA, base);
        float zB = fmaf(zp.y, pxB, base);
        bool inJ = (j >= bb.y) & (j < bb.w);
        bool inA = (iA >= bb.x) & (iA < bb.z) & inJ;
        bool inB = (iB >= bb.x) & (iB < bb.z) & inJ;
        if (inA & (zA >= bestA)) { bestA = zA; btA = __float_as_int(zp.w); }
        if (inB & (zB >= bestB)) { bestB = zB; btB = __float_as_int(zp.w); }
    }
    // S3: exact edge evaluation (reference op order) + bbox; vertex data read
    // from the LDS tri copy at wave-uniform index (broadcast, conflict-free).
#pragma unroll 2
    for (int k = cntB; k < cntC; ++k) {
        float4 zp = szp[k];
        int4 bb = sbb[k];
        const int tt = __float_as_int(zp.w);
        const float* q = &stris[tt * 9];
        float qa0 = q[0], qa1 = q[1];
        float qb0 = q[3], qb1 = q[4];
        float qc0 = q[6], qc1 = q[7];
        float day = qa1 - py, dby = qb1 - py, dcy = qc1 - py;
        float base = fmaf(zp.z, py, zp.x);
        bool inJ = (j >= bb.y) & (j < bb.w);
        {
            float dax = qa0 - pxA, dbx = qb0 - pxA, dcx = qc0 - pxA;
            float pAB = dax * dby - day * dbx;
            float pBC = dbx * dcy - dby * dcx;
            float pCA = dcx * day - dcy * dax;
            bool cov = (pAB > 0.0f) & (pBC > 0.0f) & (pCA > 0.0f) &
                       (iA >= bb.x) & (iA < bb.z) & inJ;
            float zA = fmaf(zp.y, pxA, base);
            if (cov & (zA >= bestA)) { bestA = zA; btA = tt; }
        }
        {
            float dax = qa0 - pxB, dbx = qb0 - pxB, dcx = qc0 - pxB;
            float pAB = dax * dby - day * dbx;
            float pBC = dbx * dcy - dby * dcx;
            float pCA = dcx * day - dcy * dax;
            bool cov = (pAB > 0.0f) & (pBC > 0.0f) & (pCA > 0.0f) &
                       (iB >= bb.x) & (iB < bb.z) & inJ;
            float zB = fmaf(zp.y, pxB, base);
            if (cov & (zB >= bestB)) { bestB = zB; btB = tt; }
        }
    }

    // ---- epilogue: bit-exact shade of winners (from LDS copy) ----
    ((float4*)out)[iA * SIZE + j] = shade_lds(stris, btA, pxA, py);
    ((float4*)out)[iB * SIZE + j] = shade_lds(stris, btB, pxB, py);
}

extern "C" void kernel_launch(void* const* d_in, const int* in_sizes, int n_in,
                              void* d_out, int out_size, void* d_ws, size_t ws_size,
                              hipStream_t stream) {
    const float* tris = (const float*)d_in[0];
    float* out = (float*)d_out;
    dim3 grid(SIZE / 32, SIZE / 32, 1);
    dim3 block(512, 1, 1);
    render_kernel<<<grid, block, 0, stream>>>(tris, out);
}